// Round 1
// baseline (347.147 us; speedup 1.0000x reference)
//
#include <hip/hip_runtime.h>
#include <hip/hip_bf16.h>
#include <math.h>

typedef int   v4i __attribute__((ext_vector_type(4)));
typedef float v4f __attribute__((ext_vector_type(4)));

#define B_DIM   256
#define IN_DIM  1024
#define H4      4096
#define NPLANE  4
#define WELEM   (NPLANE * IN_DIM * H4)   // 16777216 per weight tensor
#define XELEM   (B_DIM * IN_DIM)         // 262144

// ---- ws layout ----
// [0,16)        : maxes (w_ih, w_hh, b_ih, b_hh) as float bits (atomicMax on int)
// [WS_X_OFF,..) : X planes int8 [4][256][1024]  (values 0/1)
// [WS_CMP_OFF,) : cmp bytes [2][4][256][4096]
#define WS_X_OFF      (64 + 262144)
#define WS_CMP_OFF    (64 + 262144 + 1048576)

// ---------------- Pass A1: global maxes ----------------
__global__ void k_max(const float* __restrict__ wih, const float* __restrict__ whh,
                      const float* __restrict__ bih, const float* __restrict__ bhh,
                      float* __restrict__ outm) {
  int b = blockIdx.x, t = threadIdx.x;
  const float* src; long n4; int slot; long bb, nb;
  if (b < 512)       { src = wih; n4 = WELEM / 4; slot = 0; bb = b;       nb = 512; }
  else if (b < 1024) { src = whh; n4 = WELEM / 4; slot = 1; bb = b - 512; nb = 512; }
  else if (b == 1024){ src = bih; n4 = 16384 / 4; slot = 2; bb = 0;       nb = 1;   }
  else               { src = bhh; n4 = 16384 / 4; slot = 3; bb = 0;       nb = 1;   }
  const v4f* p = (const v4f*)src;
  float m = -3.4e38f;
  for (long i = bb * 256 + t; i < n4; i += nb * 256) {
    v4f v = p[i];
    m = fmaxf(m, fmaxf(fmaxf(v.x, v.y), fmaxf(v.z, v.w)));
  }
#pragma unroll
  for (int off = 32; off >= 1; off >>= 1) m = fmaxf(m, __shfl_down(m, off, 64));
  __shared__ float sm[4];
  int w = t >> 6, ln = t & 63;
  if (ln == 0) sm[w] = m;
  __syncthreads();
  if (t == 0) {
    m = fmaxf(fmaxf(sm[0], sm[1]), fmaxf(sm[2], sm[3]));
    atomicMax((int*)&outm[slot], __float_as_int(m));  // maxes are > 0 for gaussian data
  }
}

// ---------------- Pass A2: input bit-planes only ----------------
__global__ void k_prep(const float* __restrict__ input, const float* __restrict__ a1p,
                       signed char* __restrict__ X) {
  int gid = blockIdx.x * 256 + threadIdx.x;   // 0..262143
  float a1 = a1p[0];
  float x = input[gid];
  // pact_a exactly as jax: sign(x)*0.5*(|x| - ||x|-a| + a)
  float t = fabsf(x), u = fabsf(t - a1);
  float sg = (x > 0.f) ? 0.5f : ((x < 0.f) ? -0.5f : 0.f);
  float p = sg * ((t - u) + a1);
  float inp01 = (p + a1) / (a1 * 2.0f);
  float q = rintf(15.0f * inp01);              // jnp.round is half-even, matches rintf
  int qi = (int)q;
#pragma unroll
  for (int pl = 0; pl < 4; ++pl)
    X[pl * XELEM + gid] = (signed char)((qi >> (3 - pl)) & 1);
}

// ---------------- Pass B: exact digit-GEMM ----------------
// grid: x = ntile (128 tiles of 32 cols), y = sp (s*4 + plane, 8)
// block: 512 threads = 8 waves; wave w covers output rows [w*32, w*32+32)
//
// LDS layout (per buf, per digit): [n(32)][k(64 bytes)] with 16B-block XOR swizzle
//   byte(n, k) at n*64 + ((k>>4) ^ ((n>>1)&3))*16 + (k&15)
// -> ds_write_b32 (one dword per thread per digit) and ds_read_b128 are both
//    bank-conflict-free by construction (2 lanes/bank max).
__global__ __launch_bounds__(512, 4) void k_gemm(
    const float* __restrict__ Wih, const float* __restrict__ Whh,
    const float* __restrict__ Eih, const float* __restrict__ Ehh,
    const float* __restrict__ bih, const float* __restrict__ bhh,
    const float* __restrict__ ebih, const float* __restrict__ ebhh,
    const float* __restrict__ maxm,
    const signed char* __restrict__ X, unsigned char* __restrict__ cmp) {
  const int ntile = blockIdx.x;
  const int sp = blockIdx.y;
  const int s = sp >> 2, plane = sp & 3;
  const float* W = s ? Whh : Wih;
  const float* E = s ? Ehh : Eih;
  const float maxw = maxm[s];

  const int tid = threadIdx.x;
  const int wave = tid >> 6, lane = tid & 63, quad = lane >> 4, l15 = lane & 15;

  __shared__ __align__(16) unsigned char Blds[2 * 4 * 32 * 64];   // 16 KB

  // staging mapping: thread -> (col sn, k dword kq)
  const int sn = tid & 31;          // column within 32-col tile
  const int kq = tid >> 5;          // k-dword index (0..15)
  const int k0 = kq << 2;           // k byte/elem offset (0..60)
  // swizzled write offset: constant per thread (+ d*2048 + buf*8192)
  const int wr_off = sn * 64 + ((((kq >> 2) ^ ((sn >> 1) & 3)) << 4) | ((kq & 3) << 2));

  v4i acc[4][2][2];
#pragma unroll
  for (int d = 0; d < 4; ++d)
#pragma unroll
    for (int m = 0; m < 2; ++m)
#pragma unroll
      for (int n = 0; n < 2; ++n) acc[d][m][n] = (v4i){0, 0, 0, 0};

  const float* wp = W + (size_t)(plane * IN_DIM + k0) * H4 + (size_t)ntile * 32 + sn;
  const float* ep = E + (size_t)(plane * IN_DIM + k0) * H4 + (size_t)ntile * 32 + sn;

  const signed char* Xp = X + plane * XELEM;
  const int arow0 = wave * 32 + l15;

  // digitize 4 elements (k0..k0+3 of column sn) and store one dword per digit
  auto digitize_write = [&](const float wv[4], const float evv[4], int bf) {
    unsigned int pk0 = 0, pk1 = 0, pk2 = 0, pk3 = 0;
#pragma unroll
    for (int j = 0; j < 4; ++j) {
      float w = wv[j], ev = evv[j];
      float xc = fminf(fmaxf(w, -0.9921875f), 0.9921875f);
      float qv = rintf(xc * 128.f) * 0.0078125f;
      float noise = (ev * maxw) * 0.1f;
      float a = w + ((qv - w) + noise);          // exact jax f32 chain -> w_eff
      // radix-128 digits, scale 8: a = (f0 + f1/128 + f2/128^2 + f3/128^3)/8 + O(2^-25)
      float x0 = a * 8.f;    float f0 = rintf(x0); float r0 = x0 - f0;
      float x1 = r0 * 128.f; float f1 = rintf(x1); float r1 = x1 - f1;
      float x2 = r1 * 128.f; float f2 = rintf(x2); float r2 = x2 - f2;
      float x3 = r2 * 128.f; float f3 = rintf(x3);
      pk0 |= ((unsigned int)((int)f0 & 255)) << (8 * j);
      pk1 |= ((unsigned int)((int)f1 & 255)) << (8 * j);
      pk2 |= ((unsigned int)((int)f2 & 255)) << (8 * j);
      pk3 |= ((unsigned int)((int)f3 & 255)) << (8 * j);
    }
    unsigned char* base = Blds + bf * 8192 + wr_off;
    *(unsigned int*)(base)        = pk0;
    *(unsigned int*)(base + 2048) = pk1;
    *(unsigned int*)(base + 4096) = pk2;
    *(unsigned int*)(base + 6144) = pk3;
  };

  // ---- prologue: stage chunk 0 into buf 0, load A frags for chunk 0 ----
  {
    float w4[4], e4[4];
#pragma unroll
    for (int j = 0; j < 4; ++j) { w4[j] = wp[(size_t)j * H4]; e4[j] = ep[(size_t)j * H4]; }
    digitize_write(w4, e4, 0);
  }
  v4i afr[2];
  afr[0] = *(const v4i*)(Xp + (arow0) * IN_DIM + quad * 16);
  afr[1] = *(const v4i*)(Xp + (arow0 + 16) * IN_DIM + quad * 16);
  __syncthreads();

  for (int ch = 0; ch < 16; ++ch) {
    const int buf = ch & 1;
    // issue next-chunk global loads first (latency covered by MFMA below)
    float nw[4], ne[4];
    v4i anx[2]; anx[0] = afr[0]; anx[1] = afr[1];
    if (ch < 15) {
      size_t off = (size_t)(ch + 1) * 64 * H4;
#pragma unroll
      for (int j = 0; j < 4; ++j) { nw[j] = wp[off + (size_t)j * H4]; ne[j] = ep[off + (size_t)j * H4]; }
      anx[0] = *(const v4i*)(Xp + (arow0) * IN_DIM + (ch + 1) * 64 + quad * 16);
      anx[1] = *(const v4i*)(Xp + (arow0 + 16) * IN_DIM + (ch + 1) * 64 + quad * 16);
    }
    // MFMA on current buffer
    const unsigned char* rb = Blds + buf * 8192;
#pragma unroll
    for (int d = 0; d < 4; ++d) {
#pragma unroll
      for (int ns = 0; ns < 2; ++ns) {
        const int nr = ns * 16 + l15;
        v4i bfr = *(const v4i*)(rb + d * 2048 + nr * 64 + ((quad ^ ((nr >> 1) & 3)) << 4));
        acc[d][0][ns] = __builtin_amdgcn_mfma_i32_16x16x64_i8(afr[0], bfr, acc[d][0][ns], 0, 0, 0);
        acc[d][1][ns] = __builtin_amdgcn_mfma_i32_16x16x64_i8(afr[1], bfr, acc[d][1][ns], 0, 0, 0);
      }
    }
    if (ch < 15) digitize_write(nw, ne, buf ^ 1);
    afr[0] = anx[0]; afr[1] = anx[1];
    __syncthreads();
  }

  // ---- epilogue: inline threshold + exact combine + compare ----
  const float* bp  = s ? bhh : bih;
  const float* ebp = s ? ebhh : ebih;
  const float mb = maxm[2 + s];
  const double inv = 1.0 / 16777216.0;   // /(8*128^3)
  unsigned char* cp = cmp + (size_t)sp * B_DIM * H4;
#pragma unroll
  for (int ns = 0; ns < 2; ++ns) {
    int col = ntile * 32 + ns * 16 + l15;
    // bit-identical to the old k_prep thresh computation
    float bv = bp[plane * H4 + col], ev = ebp[plane * H4 + col];
    float xc = fminf(fmaxf(bv, -0.9921875f), 0.9921875f);
    float qv = rintf(xc * 128.f) * 0.0078125f;
    float noise = (ev * mb) * 0.1f;
    float beff = bv + ((qv - bv) + noise);
    double th = 0.5 - (double)beff;
#pragma unroll
    for (int ms = 0; ms < 2; ++ms) {
#pragma unroll
      for (int r = 0; r < 4; ++r) {
        long long T = ((long long)acc[0][ms][ns][r] << 21) + ((long long)acc[1][ms][ns][r] << 14)
                    + ((long long)acc[2][ms][ns][r] << 7)  +  (long long)acc[3][ms][ns][r];
        int row = wave * 32 + ms * 16 + quad * 4 + r;
        cp[(size_t)row * H4 + col] = ((double)T * inv > th) ? 1 : 0;
      }
    }
  }
}

// ---------------- Pass C: pointwise LSTM ----------------
__device__ __forceinline__ float pact_(float x, float a) {
  float t = fabsf(x), u = fabsf(t - a);
  float sg = (x > 0.f) ? 0.5f : ((x < 0.f) ? -0.5f : 0.f);
  return sg * ((t - u) + a);
}
__device__ __forceinline__ float quant_(float x, float a) {
  float xr = x / a;
  xr = fminf(fmaxf(xr, -0.9921875f), 0.9921875f);
  return rintf(xr * 128.f) * 0.0078125f * a;
}
__device__ __forceinline__ float sigm_(float x) { return 1.0f / (1.0f + expf(-x)); }

__global__ void k_pointwise(const unsigned char* __restrict__ cmp, const float* __restrict__ cx,
                            const float* a3, const float* a4, const float* a5, const float* a6,
                            const float* a7, const float* a8, const float* a9, const float* a10,
                            const float* a11, float* __restrict__ out) {
  int idx = blockIdx.x * 256 + threadIdx.x;   // 0..262143
  int b = idx >> 10, h = idx & 1023;
  float g[4];
#pragma unroll
  for (int gi = 0; gi < 4; ++gi) {
    int col = gi * 1024 + h;
    float acc = 0.f;
#pragma unroll
    for (int n = 0; n < 4; ++n) {
      int o = (int)cmp[((size_t)(0 * 4 + n) * B_DIM + b) * H4 + col]
            + (int)cmp[((size_t)(1 * 4 + n) * B_DIM + b) * H4 + col];
      float beta = (float)(8 >> n) / 15.0f;
      acc = acc + beta * (float)o;
    }
    g[gi] = acc;
  }
  float fg = quant_(pact_(sigm_(g[2]), a3[0]), a3[0]);
  float ig = quant_(pact_(sigm_(g[0]), a4[0]), a4[0]);
  float ac = quant_(pact_(tanhf(g[1]), a5[0]), a5[0]);
  float og = quant_(pact_(sigm_(g[3]), a6[0]), a6[0]);
  float cxv = cx[idx];
  float gc = quant_(pact_(cxv * fg, a7[0]), a7[0]);
  float ai = quant_(pact_(ig * ac, a8[0]), a8[0]);
  float nc = quant_(pact_(gc + ai, a9[0]), a9[0]);
  float acl = quant_(pact_(tanhf(nc), a10[0]), a10[0]);
  float nh = quant_(pact_(acl * og, a11[0]), a11[0]);
  out[idx] = nh;
  out[XELEM + idx] = nc;
}

extern "C" void kernel_launch(void* const* d_in, const int* in_sizes, int n_in,
                              void* d_out, int out_size, void* d_ws, size_t ws_size,
                              hipStream_t stream) {
  (void)in_sizes; (void)n_in; (void)out_size; (void)ws_size;
  const float* input = (const float*)d_in[0];
  const float* cx    = (const float*)d_in[2];
  const float* wih   = (const float*)d_in[3];
  const float* whh   = (const float*)d_in[4];
  const float* bih   = (const float*)d_in[5];
  const float* bhh   = (const float*)d_in[6];
  const float* ewih  = (const float*)d_in[7];
  const float* ewhh  = (const float*)d_in[8];
  const float* ebih  = (const float*)d_in[9];
  const float* ebhh  = (const float*)d_in[10];
  const float* a1    = (const float*)d_in[11];
  const float* a3    = (const float*)d_in[12];
  const float* a4    = (const float*)d_in[13];
  const float* a5    = (const float*)d_in[14];
  const float* a6    = (const float*)d_in[15];
  const float* a7    = (const float*)d_in[16];
  const float* a8    = (const float*)d_in[17];
  const float* a9    = (const float*)d_in[18];
  const float* a10   = (const float*)d_in[19];
  const float* a11   = (const float*)d_in[20];
  float* out = (float*)d_out;

  char* ws = (char*)d_ws;
  float*         maxm = (float*)ws;
  signed char*   X    = (signed char*)(ws + WS_X_OFF);
  unsigned char* cmp  = (unsigned char*)(ws + WS_CMP_OFF);

  hipMemsetAsync(ws, 0, 64, stream);
  k_max<<<1026, 256, 0, stream>>>(wih, whh, bih, bhh, maxm);
  k_prep<<<1024, 256, 0, stream>>>(input, a1, X);
  k_gemm<<<dim3(128, 8), 512, 0, stream>>>(wih, whh, ewih, ewhh, bih, bhh, ebih, ebhh,
                                           maxm, X, cmp);
  k_pointwise<<<1024, 256, 0, stream>>>(cmp, cx, a3, a4, a5, a6, a7, a8, a9, a10, a11, out);
}

// Round 3
// 341.634 us; speedup vs baseline: 1.0161x; 1.0161x over previous
//
#include <hip/hip_runtime.h>
#include <hip/hip_bf16.h>
#include <math.h>

typedef int   v4i __attribute__((ext_vector_type(4)));
typedef float v4f __attribute__((ext_vector_type(4)));

#define B_DIM   256
#define IN_DIM  1024
#define H4      4096
#define NPLANE  4
#define WELEM   (NPLANE * IN_DIM * H4)   // 16777216 per weight tensor
#define XELEM   (B_DIM * IN_DIM)         // 262144

// ---- ws layout ----
// [0,16)        : maxes (w_ih, w_hh, b_ih, b_hh) as float bits (atomicMax on int)
// [WS_X_OFF,..) : X planes int8 [4][256][1024]  (values 0/1)
// [WS_CMP_OFF,) : cmp bytes [2][4][256][4096]
#define WS_X_OFF      (64 + 262144)
#define WS_CMP_OFF    (64 + 262144 + 1048576)

// ---------------- Pass A1: global maxes ----------------
__global__ void k_max(const float* __restrict__ wih, const float* __restrict__ whh,
                      const float* __restrict__ bih, const float* __restrict__ bhh,
                      float* __restrict__ outm) {
  int b = blockIdx.x, t = threadIdx.x;
  const float* src; long n4; int slot; long bb, nb;
  if (b < 512)       { src = wih; n4 = WELEM / 4; slot = 0; bb = b;       nb = 512; }
  else if (b < 1024) { src = whh; n4 = WELEM / 4; slot = 1; bb = b - 512; nb = 512; }
  else if (b == 1024){ src = bih; n4 = 16384 / 4; slot = 2; bb = 0;       nb = 1;   }
  else               { src = bhh; n4 = 16384 / 4; slot = 3; bb = 0;       nb = 1;   }
  const v4f* p = (const v4f*)src;
  float m = -3.4e38f;
  for (long i = bb * 256 + t; i < n4; i += nb * 256) {
    v4f v = p[i];
    m = fmaxf(m, fmaxf(fmaxf(v.x, v.y), fmaxf(v.z, v.w)));
  }
#pragma unroll
  for (int off = 32; off >= 1; off >>= 1) m = fmaxf(m, __shfl_down(m, off, 64));
  __shared__ float sm[4];
  int w = t >> 6, ln = t & 63;
  if (ln == 0) sm[w] = m;
  __syncthreads();
  if (t == 0) {
    m = fmaxf(fmaxf(sm[0], sm[1]), fmaxf(sm[2], sm[3]));
    atomicMax((int*)&outm[slot], __float_as_int(m));  // maxes are > 0 for gaussian data
  }
}

// ---------------- Pass A2: input bit-planes only ----------------
__global__ void k_prep(const float* __restrict__ input, const float* __restrict__ a1p,
                       signed char* __restrict__ X) {
  int gid = blockIdx.x * 256 + threadIdx.x;   // 0..262143
  float a1 = a1p[0];
  float x = input[gid];
  // pact_a exactly as jax: sign(x)*0.5*(|x| - ||x|-a| + a)
  float t = fabsf(x), u = fabsf(t - a1);
  float sg = (x > 0.f) ? 0.5f : ((x < 0.f) ? -0.5f : 0.f);
  float p = sg * ((t - u) + a1);
  float inp01 = (p + a1) / (a1 * 2.0f);
  float q = rintf(15.0f * inp01);              // jnp.round is half-even, matches rintf
  int qi = (int)q;
#pragma unroll
  for (int pl = 0; pl < 4; ++pl)
    X[pl * XELEM + gid] = (signed char)((qi >> (3 - pl)) & 1);
}

// ---------------- Pass B: exact digit-GEMM ----------------
// grid: x = ntile (128 tiles of 32 cols), y = sp (s*4 + plane, 8)
// block: 512 threads = 8 waves; wave w covers output rows [w*32, w*32+32)
//
// Staging: vector v4f global loads (lane = 1 k-row x 4 cols), digitize to 4
// digit-bytes per element, then a 4x4 in-register byte transpose across lanes
// {l, l+8, l+16, l+24} (2x shfl_xor + 2x v_perm per digit) produces one
// k-contiguous dword per lane per digit, written with the swizzled layout:
//   byte(n, k) at n*64 + ((k>>4) ^ ((n>>1)&3))*16 + (k&15)
// Read side (ds_read_b128 B-fragments) identical to the verified round-1 kernel.
// W/E HBM streams are prefetched 2 chunks deep so digitize never waits on HBM.
__global__ __launch_bounds__(512, 2) void k_gemm(
    const float* __restrict__ Wih, const float* __restrict__ Whh,
    const float* __restrict__ Eih, const float* __restrict__ Ehh,
    const float* __restrict__ bih, const float* __restrict__ bhh,
    const float* __restrict__ ebih, const float* __restrict__ ebhh,
    const float* __restrict__ maxm,
    const signed char* __restrict__ X, unsigned char* __restrict__ cmp) {
  const int ntile = blockIdx.x;
  const int sp = blockIdx.y;
  const int s = sp >> 2, plane = sp & 3;
  const float* W = s ? Whh : Wih;
  const float* E = s ? Ehh : Eih;
  const float maxw = maxm[s];

  const int tid = threadIdx.x;
  const int wave = tid >> 6, lane = tid & 63, quad = lane >> 4, l15 = lane & 15;

  __shared__ __align__(16) unsigned char Blds[2 * 4 * 32 * 64];   // 16 KB

  // global load mapping: k-row kl (0..63 within chunk), cols nc4..nc4+3
  const int kl  = tid >> 3;          // 8 rows per wave
  const int nc4 = (tid & 7) << 2;
  // transpose-group position: lanes {l0, l0+8, l0+16, l0+24} hold rows p=0..3
  const int p  = (lane >> 3) & 3;
  const int sq = p & 1, qq = p >> 1;
  const unsigned sel1 = sq ? 0x03070206u : 0x05010400u;
  const unsigned sel2 = qq ? 0x03020706u : 0x05040100u;
  // post-transpose write coords: column snW, k-dword kqW
  const int snW = nc4 + 2 * sq + qq;            // 0..31, bijective per half-wave
  const int kqW = (wave << 1) + (lane >> 5);    // 0..15
  const int wr_off = snW * 64 + ((((kqW >> 2) ^ ((snW >> 1) & 3)) << 4) | ((kqW & 3) << 2));

  v4i acc[4][2][2];
#pragma unroll
  for (int d = 0; d < 4; ++d)
#pragma unroll
    for (int m = 0; m < 2; ++m)
#pragma unroll
      for (int n = 0; n < 2; ++n) acc[d][m][n] = (v4i){0, 0, 0, 0};

  const size_t cstep = (size_t)64 * H4;  // chunk stride (floats)
  const float* wp = W + ((size_t)plane * IN_DIM + kl) * H4 + (size_t)ntile * 32 + nc4;
  const float* ep = E + ((size_t)plane * IN_DIM + kl) * H4 + (size_t)ntile * 32 + nc4;

  const signed char* Xp = X + plane * XELEM;
  const int arow0 = wave * 32 + l15;

  // digitize 4 elements (cols nc4..+3 at row kl) -> 4 digit dwords (byte j = col j)
  auto digitize4 = [&](v4f w4, v4f e4, unsigned pk[4]) {
    pk[0] = pk[1] = pk[2] = pk[3] = 0;
#pragma unroll
    for (int j = 0; j < 4; ++j) {
      float w = w4[j], ev = e4[j];
      float xc = fminf(fmaxf(w, -0.9921875f), 0.9921875f);
      float qv = rintf(xc * 128.f) * 0.0078125f;
      float noise = (ev * maxw) * 0.1f;
      float a = w + ((qv - w) + noise);          // exact jax f32 chain -> w_eff
      // radix-128 digits, scale 8: a = (f0 + f1/128 + f2/128^2 + f3/128^3)/8 + O(2^-25)
      float x0 = a * 8.f;    float f0 = rintf(x0); float r0 = x0 - f0;
      float x1 = r0 * 128.f; float f1 = rintf(x1); float r1 = x1 - f1;
      float x2 = r1 * 128.f; float f2 = rintf(x2); float r2 = x2 - f2;
      float x3 = r2 * 128.f; float f3 = rintf(x3);
      pk[0] |= ((unsigned)((int)f0 & 255)) << (8 * j);
      pk[1] |= ((unsigned)((int)f1 & 255)) << (8 * j);
      pk[2] |= ((unsigned)((int)f2 & 255)) << (8 * j);
      pk[3] |= ((unsigned)((int)f3 & 255)) << (8 * j);
    }
  };
  // 4x4 byte transpose across lanes {^8, ^16}, then swizzled dword write
  auto transpose_write = [&](const unsigned pk[4], int bf) {
    unsigned char* base = Blds + bf * 8192 + wr_off;
#pragma unroll
    for (int d = 0; d < 4; ++d) {
      unsigned A = pk[d];
      unsigned t = (unsigned)__shfl_xor((int)A, 8, 64);
      unsigned D = __builtin_amdgcn_perm(t, A, sel1);    // cols {2s,2s+1}, rows {2q,2q+1}
      unsigned Ex = (unsigned)__shfl_xor((int)D, 16, 64);
      unsigned o = __builtin_amdgcn_perm(Ex, D, sel2);   // column 2s+q, rows 0..3
      *(unsigned*)(base + d * 2048) = o;
    }
  };

  // ---- prologue ----
  unsigned pk[4];
  {
    v4f w4 = *(const v4f*)wp;
    v4f e4 = *(const v4f*)ep;
    digitize4(w4, e4, pk);
    transpose_write(pk, 0);
  }
  v4f wA = *(const v4f*)(wp + cstep);    // chunk 1 in flight
  v4f eA = *(const v4f*)(ep + cstep);
  v4i afr[2];
  afr[0] = *(const v4i*)(Xp + (arow0) * IN_DIM + quad * 16);
  afr[1] = *(const v4i*)(Xp + (arow0 + 16) * IN_DIM + quad * 16);
  __syncthreads();

  for (int ch = 0; ch < 16; ++ch) {
    const int buf = ch & 1;
    // issue chunk ch+2 W/E loads (2-deep) and chunk ch+1 X loads (1-deep)
    v4f wB = wA, eB = eA;
    v4i anx0 = afr[0], anx1 = afr[1];
    if (ch < 14) {
      wB = *(const v4f*)(wp + (size_t)(ch + 2) * cstep);
      eB = *(const v4f*)(ep + (size_t)(ch + 2) * cstep);
    }
    if (ch < 15) {
      anx0 = *(const v4i*)(Xp + (arow0) * IN_DIM + (ch + 1) * 64 + quad * 16);
      anx1 = *(const v4i*)(Xp + (arow0 + 16) * IN_DIM + (ch + 1) * 64 + quad * 16);
    }
    // MFMA on current buffer
    const unsigned char* rb = Blds + buf * 8192;
#pragma unroll
    for (int d = 0; d < 4; ++d) {
#pragma unroll
      for (int ns = 0; ns < 2; ++ns) {
        const int nr = ns * 16 + l15;
        v4i bfr = *(const v4i*)(rb + d * 2048 + nr * 64 + ((quad ^ ((nr >> 1) & 3)) << 4));
        acc[d][0][ns] = __builtin_amdgcn_mfma_i32_16x16x64_i8(afr[0], bfr, acc[d][0][ns], 0, 0, 0);
        acc[d][1][ns] = __builtin_amdgcn_mfma_i32_16x16x64_i8(afr[1], bfr, acc[d][1][ns], 0, 0, 0);
      }
    }
    // digitize chunk ch+1 (its loads have been in flight a full iteration)
    if (ch < 15) {
      digitize4(wA, eA, pk);
      transpose_write(pk, buf ^ 1);
      wA = wB; eA = eB;
    }
    afr[0] = anx0; afr[1] = anx1;
    __syncthreads();
  }

  // ---- epilogue: inline threshold + exact combine + compare ----
  const float* bp  = s ? bhh : bih;
  const float* ebp = s ? ebhh : ebih;
  const float mb = maxm[2 + s];
  const double inv = 1.0 / 16777216.0;   // /(8*128^3)
  unsigned char* cp = cmp + (size_t)sp * B_DIM * H4;
#pragma unroll
  for (int ns = 0; ns < 2; ++ns) {
    int col = ntile * 32 + ns * 16 + l15;
    float bv = bp[plane * H4 + col], ev = ebp[plane * H4 + col];
    float xc = fminf(fmaxf(bv, -0.9921875f), 0.9921875f);
    float qv = rintf(xc * 128.f) * 0.0078125f;
    float noise = (ev * mb) * 0.1f;
    float beff = bv + ((qv - bv) + noise);
    double th = 0.5 - (double)beff;
#pragma unroll
    for (int ms = 0; ms < 2; ++ms) {
#pragma unroll
      for (int r = 0; r < 4; ++r) {
        long long T = ((long long)acc[0][ms][ns][r] << 21) + ((long long)acc[1][ms][ns][r] << 14)
                    + ((long long)acc[2][ms][ns][r] << 7)  +  (long long)acc[3][ms][ns][r];
        int row = wave * 32 + ms * 16 + quad * 4 + r;
        cp[(size_t)row * H4 + col] = ((double)T * inv > th) ? 1 : 0;
      }
    }
  }
}

// ---------------- Pass C: pointwise LSTM ----------------
__device__ __forceinline__ float pact_(float x, float a) {
  float t = fabsf(x), u = fabsf(t - a);
  float sg = (x > 0.f) ? 0.5f : ((x < 0.f) ? -0.5f : 0.f);
  return sg * ((t - u) + a);
}
__device__ __forceinline__ float quant_(float x, float a) {
  float xr = x / a;
  xr = fminf(fmaxf(xr, -0.9921875f), 0.9921875f);
  return rintf(xr * 128.f) * 0.0078125f * a;
}
__device__ __forceinline__ float sigm_(float x) { return 1.0f / (1.0f + expf(-x)); }

__global__ void k_pointwise(const unsigned char* __restrict__ cmp, const float* __restrict__ cx,
                            const float* a3, const float* a4, const float* a5, const float* a6,
                            const float* a7, const float* a8, const float* a9, const float* a10,
                            const float* a11, float* __restrict__ out) {
  int idx = blockIdx.x * 256 + threadIdx.x;   // 0..262143
  int b = idx >> 10, h = idx & 1023;
  float g[4];
#pragma unroll
  for (int gi = 0; gi < 4; ++gi) {
    int col = gi * 1024 + h;
    float acc = 0.f;
#pragma unroll
    for (int n = 0; n < 4; ++n) {
      int o = (int)cmp[((size_t)(0 * 4 + n) * B_DIM + b) * H4 + col]
            + (int)cmp[((size_t)(1 * 4 + n) * B_DIM + b) * H4 + col];
      float beta = (float)(8 >> n) / 15.0f;
      acc = acc + beta * (float)o;
    }
    g[gi] = acc;
  }
  float fg = quant_(pact_(sigm_(g[2]), a3[0]), a3[0]);
  float ig = quant_(pact_(sigm_(g[0]), a4[0]), a4[0]);
  float ac = quant_(pact_(tanhf(g[1]), a5[0]), a5[0]);
  float og = quant_(pact_(sigm_(g[3]), a6[0]), a6[0]);
  float cxv = cx[idx];
  float gc = quant_(pact_(cxv * fg, a7[0]), a7[0]);
  float ai = quant_(pact_(ig * ac, a8[0]), a8[0]);
  float nc = quant_(pact_(gc + ai, a9[0]), a9[0]);
  float acl = quant_(pact_(tanhf(nc), a10[0]), a10[0]);
  float nh = quant_(pact_(acl * og, a11[0]), a11[0]);
  out[idx] = nh;
  out[XELEM + idx] = nc;
}

extern "C" void kernel_launch(void* const* d_in, const int* in_sizes, int n_in,
                              void* d_out, int out_size, void* d_ws, size_t ws_size,
                              hipStream_t stream) {
  (void)in_sizes; (void)n_in; (void)out_size; (void)ws_size;
  const float* input = (const float*)d_in[0];
  const float* cx    = (const float*)d_in[2];
  const float* wih   = (const float*)d_in[3];
  const float* whh   = (const float*)d_in[4];
  const float* bih   = (const float*)d_in[5];
  const float* bhh   = (const float*)d_in[6];
  const float* ewih  = (const float*)d_in[7];
  const float* ewhh  = (const float*)d_in[8];
  const float* ebih  = (const float*)d_in[9];
  const float* ebhh  = (const float*)d_in[10];
  const float* a1    = (const float*)d_in[11];
  const float* a3    = (const float*)d_in[12];
  const float* a4    = (const float*)d_in[13];
  const float* a5    = (const float*)d_in[14];
  const float* a6    = (const float*)d_in[15];
  const float* a7    = (const float*)d_in[16];
  const float* a8    = (const float*)d_in[17];
  const float* a9    = (const float*)d_in[18];
  const float* a10   = (const float*)d_in[19];
  const float* a11   = (const float*)d_in[20];
  float* out = (float*)d_out;

  char* ws = (char*)d_ws;
  float*         maxm = (float*)ws;
  signed char*   X    = (signed char*)(ws + WS_X_OFF);
  unsigned char* cmp  = (unsigned char*)(ws + WS_CMP_OFF);

  hipMemsetAsync(ws, 0, 64, stream);
  k_max<<<1026, 256, 0, stream>>>(wih, whh, bih, bhh, maxm);
  k_prep<<<1024, 256, 0, stream>>>(input, a1, X);
  k_gemm<<<dim3(128, 8), 512, 0, stream>>>(wih, whh, ewih, ewhh, bih, bhh, ebih, ebhh,
                                           maxm, X, cmp);
  k_pointwise<<<1024, 256, 0, stream>>>(cmp, cx, a3, a4, a5, a6, a7, a8, a9, a10, a11, out);
}

// Round 4
// 333.556 us; speedup vs baseline: 1.0407x; 1.0242x over previous
//
#include <hip/hip_runtime.h>
#include <hip/hip_bf16.h>
#include <math.h>

typedef int   v4i __attribute__((ext_vector_type(4)));
typedef float v4f __attribute__((ext_vector_type(4)));

#define B_DIM   256
#define IN_DIM  1024
#define H4      4096
#define NPLANE  4
#define WELEM   (NPLANE * IN_DIM * H4)   // 16777216 per weight tensor
#define XELEM   (B_DIM * IN_DIM)         // 262144

// ---- ws layout ----
// [0,16)        : maxes (w_ih, w_hh, b_ih, b_hh) as float bits (atomicMax on int)
// [64, +4096)   : rowsumX int [4][256]  (per-plane, per-batch-row sums of X bits)
// [WS_X_OFF,..) : X planes int8 [4][256][1024]  (values 0/1)
// [WS_CMP_OFF,) : cmp bytes [2][4][256][4096]
#define WS_RS_OFF     64
#define WS_X_OFF      (64 + 262144)
#define WS_CMP_OFF    (64 + 262144 + 1048576)

// ---------------- Pass A1: global maxes ----------------
__global__ void k_max(const float* __restrict__ wih, const float* __restrict__ whh,
                      const float* __restrict__ bih, const float* __restrict__ bhh,
                      float* __restrict__ outm) {
  int b = blockIdx.x, t = threadIdx.x;
  const float* src; long n4; int slot; long bb, nb;
  if (b < 512)       { src = wih; n4 = WELEM / 4; slot = 0; bb = b;       nb = 512; }
  else if (b < 1024) { src = whh; n4 = WELEM / 4; slot = 1; bb = b - 512; nb = 512; }
  else if (b == 1024){ src = bih; n4 = 16384 / 4; slot = 2; bb = 0;       nb = 1;   }
  else               { src = bhh; n4 = 16384 / 4; slot = 3; bb = 0;       nb = 1;   }
  const v4f* p = (const v4f*)src;
  float m = -3.4e38f;
  for (long i = bb * 256 + t; i < n4; i += nb * 256) {
    v4f v = p[i];
    m = fmaxf(m, fmaxf(fmaxf(v.x, v.y), fmaxf(v.z, v.w)));
  }
#pragma unroll
  for (int off = 32; off >= 1; off >>= 1) m = fmaxf(m, __shfl_down(m, off, 64));
  __shared__ float sm[4];
  int w = t >> 6, ln = t & 63;
  if (ln == 0) sm[w] = m;
  __syncthreads();
  if (t == 0) {
    m = fmaxf(fmaxf(sm[0], sm[1]), fmaxf(sm[2], sm[3]));
    atomicMax((int*)&outm[slot], __float_as_int(m));  // maxes are > 0 for gaussian data
  }
}

// ---------------- Pass A2: input bit-planes + per-row bit sums ----------------
__global__ void k_prep(const float* __restrict__ input, const float* __restrict__ a1p,
                       signed char* __restrict__ X, int* __restrict__ rowsum) {
  int tid = threadIdx.x;
  int gid = blockIdx.x * 256 + tid;   // 0..262143
  float a1 = a1p[0];
  float x = input[gid];
  // pact_a exactly as jax: sign(x)*0.5*(|x| - ||x|-a| + a)
  float t = fabsf(x), u = fabsf(t - a1);
  float sg = (x > 0.f) ? 0.5f : ((x < 0.f) ? -0.5f : 0.f);
  float p = sg * ((t - u) + a1);
  float inp01 = (p + a1) / (a1 * 2.0f);
  float q = rintf(15.0f * inp01);              // jnp.round is half-even, matches rintf
  int qi = (int)q;
#pragma unroll
  for (int pl = 0; pl < 4; ++pl)
    X[pl * XELEM + gid] = (signed char)((qi >> (3 - pl)) & 1);

  // per-(plane,row) sums of the bit planes, for the biased-digit correction in k_gemm.
  // pack the 4 plane bits into 4 bytes of one int; per-wave byte sums <= 64, no carry.
  int v = ((qi >> 3) & 1) | (((qi >> 2) & 1) << 8) | (((qi >> 1) & 1) << 16) | ((qi & 1) << 24);
#pragma unroll
  for (int off = 32; off >= 1; off >>= 1) v += __shfl_down(v, off, 64);
  __shared__ int sv[4];
  int wid = tid >> 6, ln = tid & 63;
  if (ln == 0) sv[wid] = v;
  __syncthreads();
  if (tid == 0) {
    int b = blockIdx.x >> 2;   // batch row (1024 cols = 4 blocks per row)
#pragma unroll
    for (int pl = 0; pl < 4; ++pl) {
      int cnt = ((sv[0] >> (8 * pl)) & 255) + ((sv[1] >> (8 * pl)) & 255)
              + ((sv[2] >> (8 * pl)) & 255) + ((sv[3] >> (8 * pl)) & 255);
      atomicAdd(&rowsum[pl * 256 + b], cnt);
    }
  }
}

// ---------------- Pass B: exact digit-GEMM ----------------
// grid: x = ntile (128 tiles of 32 cols), y = sp (s*4 + plane, 8)
// block: 512 threads = 8 waves; wave w covers output rows [w*32, w*32+32)
//
// Digitization (exact): a = w_eff (exact jax f32 chain). n = rintf(a*2^24) is
// exact (x2^24 is an exponent shift; integers >= 2^24 are already exact).
// Provably equal to the nested radix-128 rint chain (Sterbenz at every level;
// half-even ties match because all higher digit terms are multiples of 128).
// m = n + 2^27 in [0, 2^28) for |a| < 8; unsigned base-128 digits
// u_i = (m >> 7i) & 127 all fit signed i8. The GEMM then computes
// T = sum_i acc_i << (7i) - (rowsumX << 27), identical integer to before.
//
// Staging: v4f global loads (lane = 1 k-row x 4 cols), digitize -> 4 digit
// dwords (byte j = col j), 4x4 byte transpose across lanes {l,l+8,l+16,l+24}
// (2x shfl_xor + 2x v_perm per digit), swizzled dword LDS writes:
//   byte(n, k) at n*64 + ((k>>4) ^ ((n>>1)&3))*16 + (k&15)
// Read side (ds_read_b128 B-fragments) identical to the verified round-1 kernel.
// W/E HBM streams are prefetched 2 chunks deep so digitize never waits on HBM.
__global__ __launch_bounds__(512, 2) void k_gemm(
    const float* __restrict__ Wih, const float* __restrict__ Whh,
    const float* __restrict__ Eih, const float* __restrict__ Ehh,
    const float* __restrict__ bih, const float* __restrict__ bhh,
    const float* __restrict__ ebih, const float* __restrict__ ebhh,
    const float* __restrict__ maxm, const int* __restrict__ rowsum,
    const signed char* __restrict__ X, unsigned char* __restrict__ cmp) {
  const int ntile = blockIdx.x;
  const int sp = blockIdx.y;
  const int s = sp >> 2, plane = sp & 3;
  const float* W = s ? Whh : Wih;
  const float* E = s ? Ehh : Eih;
  const float maxw = maxm[s];

  const int tid = threadIdx.x;
  const int wave = tid >> 6, lane = tid & 63, quad = lane >> 4, l15 = lane & 15;

  __shared__ __align__(16) unsigned char Blds[2 * 4 * 32 * 64];   // 16 KB

  // global load mapping: k-row kl (0..63 within chunk), cols nc4..nc4+3
  const int kl  = tid >> 3;          // 8 rows per wave
  const int nc4 = (tid & 7) << 2;
  // transpose-group position: lanes {l0, l0+8, l0+16, l0+24} hold rows p=0..3
  const int p  = (lane >> 3) & 3;
  const int sq = p & 1, qq = p >> 1;
  const unsigned sel1 = sq ? 0x03070206u : 0x05010400u;
  const unsigned sel2 = qq ? 0x03020706u : 0x05040100u;
  // post-transpose write coords: column snW, k-dword kqW
  const int snW = nc4 + 2 * sq + qq;            // 0..31, bijective per half-wave
  const int kqW = (wave << 1) + (lane >> 5);    // 0..15
  const int wr_off = snW * 64 + ((((kqW >> 2) ^ ((snW >> 1) & 3)) << 4) | ((kqW & 3) << 2));

  v4i acc[4][2][2];
#pragma unroll
  for (int d = 0; d < 4; ++d)
#pragma unroll
    for (int m = 0; m < 2; ++m)
#pragma unroll
      for (int n = 0; n < 2; ++n) acc[d][m][n] = (v4i){0, 0, 0, 0};

  const size_t cstep = (size_t)64 * H4;  // chunk stride (floats)
  const float* wp = W + ((size_t)plane * IN_DIM + kl) * H4 + (size_t)ntile * 32 + nc4;
  const float* ep = E + ((size_t)plane * IN_DIM + kl) * H4 + (size_t)ntile * 32 + nc4;

  const signed char* Xp = X + plane * XELEM;
  const int arow0 = wave * 32 + l15;

  // digitize 4 elements (cols nc4..+3 at row kl) -> 4 digit dwords (byte j = col j)
  auto digitize4 = [&](v4f w4, v4f e4, unsigned pk[4]) {
    int mm[4];
#pragma unroll
    for (int j = 0; j < 4; ++j) {
      float w = w4[j], ev = e4[j];
      float xc = fminf(fmaxf(w, -0.9921875f), 0.9921875f);
      float qv = rintf(xc * 128.f) * 0.0078125f;
      float noise = (ev * maxw) * 0.1f;
      float a = w + ((qv - w) + noise);          // exact jax f32 chain -> w_eff
      mm[j] = (int)rintf(a * 16777216.0f) + (1 << 27);   // biased, in [0, 2^28)
    }
#pragma unroll
    for (int d = 0; d < 4; ++d) {
      const int sh = 21 - 7 * d;
      unsigned a0 = (unsigned)(mm[0] >> sh);
      unsigned a1 = (unsigned)(mm[1] >> sh);
      unsigned a2 = (unsigned)(mm[2] >> sh);
      unsigned a3 = (unsigned)(mm[3] >> sh);
      unsigned t1 = __builtin_amdgcn_perm(a1, a0, 0x00000400u);  // [a0.b0, a1.b0, ., .]
      unsigned t2 = __builtin_amdgcn_perm(a3, a2, 0x00000400u);  // [a2.b0, a3.b0, ., .]
      pk[d] = __builtin_amdgcn_perm(t2, t1, 0x05040100u) & 0x7f7f7f7fu;
    }
  };
  // 4x4 byte transpose across lanes {^8, ^16}, then swizzled dword write
  auto transpose_write = [&](const unsigned pk[4], int bf) {
    unsigned char* base = Blds + bf * 8192 + wr_off;
#pragma unroll
    for (int d = 0; d < 4; ++d) {
      unsigned A = pk[d];
      unsigned t = (unsigned)__shfl_xor((int)A, 8, 64);
      unsigned D = __builtin_amdgcn_perm(t, A, sel1);    // cols {2s,2s+1}, rows {2q,2q+1}
      unsigned Ex = (unsigned)__shfl_xor((int)D, 16, 64);
      unsigned o = __builtin_amdgcn_perm(Ex, D, sel2);   // column 2s+q, rows 0..3
      *(unsigned*)(base + d * 2048) = o;
    }
  };

  // ---- prologue ----
  unsigned pk[4];
  {
    v4f w4 = *(const v4f*)wp;
    v4f e4 = *(const v4f*)ep;
    digitize4(w4, e4, pk);
    transpose_write(pk, 0);
  }
  v4f wA = *(const v4f*)(wp + cstep);    // chunk 1 in flight
  v4f eA = *(const v4f*)(ep + cstep);
  v4i afr[2];
  afr[0] = *(const v4i*)(Xp + (arow0) * IN_DIM + quad * 16);
  afr[1] = *(const v4i*)(Xp + (arow0 + 16) * IN_DIM + quad * 16);
  __syncthreads();

  for (int ch = 0; ch < 16; ++ch) {
    const int buf = ch & 1;
    // issue chunk ch+2 W/E loads (2-deep) and chunk ch+1 X loads (1-deep)
    v4f wB = wA, eB = eA;
    v4i anx0 = afr[0], anx1 = afr[1];
    if (ch < 14) {
      wB = *(const v4f*)(wp + (size_t)(ch + 2) * cstep);
      eB = *(const v4f*)(ep + (size_t)(ch + 2) * cstep);
    }
    if (ch < 15) {
      anx0 = *(const v4i*)(Xp + (arow0) * IN_DIM + (ch + 1) * 64 + quad * 16);
      anx1 = *(const v4i*)(Xp + (arow0 + 16) * IN_DIM + (ch + 1) * 64 + quad * 16);
    }
    // MFMA on current buffer
    const unsigned char* rb = Blds + buf * 8192;
#pragma unroll
    for (int d = 0; d < 4; ++d) {
#pragma unroll
      for (int ns = 0; ns < 2; ++ns) {
        const int nr = ns * 16 + l15;
        v4i bfr = *(const v4i*)(rb + d * 2048 + nr * 64 + ((quad ^ ((nr >> 1) & 3)) << 4));
        acc[d][0][ns] = __builtin_amdgcn_mfma_i32_16x16x64_i8(afr[0], bfr, acc[d][0][ns], 0, 0, 0);
        acc[d][1][ns] = __builtin_amdgcn_mfma_i32_16x16x64_i8(afr[1], bfr, acc[d][1][ns], 0, 0, 0);
      }
    }
    // digitize chunk ch+1 (its loads have been in flight a full iteration)
    if (ch < 15) {
      digitize4(wA, eA, pk);
      transpose_write(pk, buf ^ 1);
      wA = wB; eA = eB;
    }
    afr[0] = anx0; afr[1] = anx1;
    __syncthreads();
  }

  // ---- epilogue: inline threshold + exact combine + compare ----
  const float* bp  = s ? bhh : bih;
  const float* ebp = s ? ebhh : ebih;
  const float mb = maxm[2 + s];
  const int* rs = rowsum + plane * 256;
  const double inv = 1.0 / 16777216.0;   // /(8*128^3)
  unsigned char* cp = cmp + (size_t)sp * B_DIM * H4;
#pragma unroll
  for (int ns = 0; ns < 2; ++ns) {
    int col = ntile * 32 + ns * 16 + l15;
    float bv = bp[plane * H4 + col], ev = ebp[plane * H4 + col];
    float xc = fminf(fmaxf(bv, -0.9921875f), 0.9921875f);
    float qv = rintf(xc * 128.f) * 0.0078125f;
    float noise = (ev * mb) * 0.1f;
    float beff = bv + ((qv - bv) + noise);
    double th = 0.5 - (double)beff;
#pragma unroll
    for (int ms = 0; ms < 2; ++ms) {
#pragma unroll
      for (int r = 0; r < 4; ++r) {
        int row = wave * 32 + ms * 16 + quad * 4 + r;
        long long T = ((long long)acc[0][ms][ns][r] << 21) + ((long long)acc[1][ms][ns][r] << 14)
                    + ((long long)acc[2][ms][ns][r] << 7)  +  (long long)acc[3][ms][ns][r]
                    - ((long long)rs[row] << 27);          // remove digit bias
        cp[(size_t)row * H4 + col] = ((double)T * inv > th) ? 1 : 0;
      }
    }
  }
}

// ---------------- Pass C: pointwise LSTM ----------------
__device__ __forceinline__ float pact_(float x, float a) {
  float t = fabsf(x), u = fabsf(t - a);
  float sg = (x > 0.f) ? 0.5f : ((x < 0.f) ? -0.5f : 0.f);
  return sg * ((t - u) + a);
}
__device__ __forceinline__ float quant_(float x, float a) {
  float xr = x / a;
  xr = fminf(fmaxf(xr, -0.9921875f), 0.9921875f);
  return rintf(xr * 128.f) * 0.0078125f * a;
}
__device__ __forceinline__ float sigm_(float x) { return 1.0f / (1.0f + expf(-x)); }

__global__ void k_pointwise(const unsigned char* __restrict__ cmp, const float* __restrict__ cx,
                            const float* a3, const float* a4, const float* a5, const float* a6,
                            const float* a7, const float* a8, const float* a9, const float* a10,
                            const float* a11, float* __restrict__ out) {
  int idx = blockIdx.x * 256 + threadIdx.x;   // 0..262143
  int b = idx >> 10, h = idx & 1023;
  float g[4];
#pragma unroll
  for (int gi = 0; gi < 4; ++gi) {
    int col = gi * 1024 + h;
    float acc = 0.f;
#pragma unroll
    for (int n = 0; n < 4; ++n) {
      int o = (int)cmp[((size_t)(0 * 4 + n) * B_DIM + b) * H4 + col]
            + (int)cmp[((size_t)(1 * 4 + n) * B_DIM + b) * H4 + col];
      float beta = (float)(8 >> n) / 15.0f;
      acc = acc + beta * (float)o;
    }
    g[gi] = acc;
  }
  float fg = quant_(pact_(sigm_(g[2]), a3[0]), a3[0]);
  float ig = quant_(pact_(sigm_(g[0]), a4[0]), a4[0]);
  float ac = quant_(pact_(tanhf(g[1]), a5[0]), a5[0]);
  float og = quant_(pact_(sigm_(g[3]), a6[0]), a6[0]);
  float cxv = cx[idx];
  float gc = quant_(pact_(cxv * fg, a7[0]), a7[0]);
  float ai = quant_(pact_(ig * ac, a8[0]), a8[0]);
  float nc = quant_(pact_(gc + ai, a9[0]), a9[0]);
  float acl = quant_(pact_(tanhf(nc), a10[0]), a10[0]);
  float nh = quant_(pact_(acl * og, a11[0]), a11[0]);
  out[idx] = nh;
  out[XELEM + idx] = nc;
}

extern "C" void kernel_launch(void* const* d_in, const int* in_sizes, int n_in,
                              void* d_out, int out_size, void* d_ws, size_t ws_size,
                              hipStream_t stream) {
  (void)in_sizes; (void)n_in; (void)out_size; (void)ws_size;
  const float* input = (const float*)d_in[0];
  const float* cx    = (const float*)d_in[2];
  const float* wih   = (const float*)d_in[3];
  const float* whh   = (const float*)d_in[4];
  const float* bih   = (const float*)d_in[5];
  const float* bhh   = (const float*)d_in[6];
  const float* ewih  = (const float*)d_in[7];
  const float* ewhh  = (const float*)d_in[8];
  const float* ebih  = (const float*)d_in[9];
  const float* ebhh  = (const float*)d_in[10];
  const float* a1    = (const float*)d_in[11];
  const float* a3    = (const float*)d_in[12];
  const float* a4    = (const float*)d_in[13];
  const float* a5    = (const float*)d_in[14];
  const float* a6    = (const float*)d_in[15];
  const float* a7    = (const float*)d_in[16];
  const float* a8    = (const float*)d_in[17];
  const float* a9    = (const float*)d_in[18];
  const float* a10   = (const float*)d_in[19];
  const float* a11   = (const float*)d_in[20];
  float* out = (float*)d_out;

  char* ws = (char*)d_ws;
  float*         maxm   = (float*)ws;
  int*           rowsum = (int*)(ws + WS_RS_OFF);
  signed char*   X      = (signed char*)(ws + WS_X_OFF);
  unsigned char* cmp    = (unsigned char*)(ws + WS_CMP_OFF);

  hipMemsetAsync(ws, 0, 64 + 4096, stream);
  k_max<<<1026, 256, 0, stream>>>(wih, whh, bih, bhh, maxm);
  k_prep<<<1024, 256, 0, stream>>>(input, a1, X, rowsum);
  k_gemm<<<dim3(128, 8), 512, 0, stream>>>(wih, whh, ewih, ewhh, bih, bhh, ebih, ebhh,
                                           maxm, rowsum, X, cmp);
  k_pointwise<<<1024, 256, 0, stream>>>(cmp, cx, a3, a4, a5, a6, a7, a8, a9, a10, a11, out);
}